// Round 3
// baseline (765.649 us; speedup 1.0000x reference)
//
#include <hip/hip_runtime.h>

#define IN_F   8192
#define OUT_F  16384
#define BATCH  32
#define KT     1024                 // codes per row per staged tile
#define NT     (IN_F / KT)          // 8 tiles per block
#define PITCH  1040                 // 1024 B row + 16 B pad (bank shift 4/row)

typedef __attribute__((ext_vector_type(8))) short  bf16x8;
typedef __attribute__((ext_vector_type(4))) float  f32x4;

// fp32 -> bf16 bits, round-to-nearest-even
__device__ __forceinline__ unsigned f2bf(float f) {
    unsigned u = __builtin_bit_cast(unsigned, f);
    return (u + 0x7fffu + ((u >> 16) & 1u)) >> 16;
}

// pack two exact-integer floats (<256) into {bf16(fb) hi, bf16(fa) lo}
__device__ __forceinline__ unsigned pk_ff(float fa, float fb) {
    unsigned ua = __builtin_bit_cast(unsigned, fa);
    unsigned ub = __builtin_bit_cast(unsigned, fb);
#if __has_builtin(__builtin_amdgcn_perm)
    return __builtin_amdgcn_perm(ub, ua, 0x07060302u);  // {ub.hi, ua.hi}
#else
    return (ua >> 16) | (ub & 0xffff0000u);
#endif
}

// async global->LDS DMA, 16 B/lane, dest = wave-uniform base + lane*16
__device__ __forceinline__ void async_copy16(const void* g, void* l) {
    __builtin_amdgcn_global_load_lds(
        (const __attribute__((address_space(1))) unsigned*)g,
        (__attribute__((address_space(3))) unsigned*)l,
        16, 0, 0);
}

// xbf[b][k] = bf16(x[b][k] * s), sumx[b] = sum_k x[b][k];  s = lut[129]
// (lut is exactly linear: lut[c] = (c-128)*s, so codes stay integer in bf16)
__global__ __launch_bounds__(256) void prep_kernel(
        const float* __restrict__ x, const float* __restrict__ lut,
        unsigned short* __restrict__ xbf, float* __restrict__ sumx) {
    const int b = blockIdx.x;
    const int t = threadIdx.x;
    const float s = lut[129];
    const float4* xr = (const float4*)(x + b * IN_F);
    ushort4* xo = (ushort4*)(xbf + b * IN_F);
    float acc = 0.f;
    #pragma unroll
    for (int i = 0; i < IN_F / 4 / 256; ++i) {
        float4 v = xr[t + i * 256];
        acc += v.x + v.y + v.z + v.w;
        ushort4 o;
        o.x = (unsigned short)f2bf(v.x * s);
        o.y = (unsigned short)f2bf(v.y * s);
        o.z = (unsigned short)f2bf(v.z * s);
        o.w = (unsigned short)f2bf(v.w * s);
        xo[t + i * 256] = o;
    }
    __shared__ float red[256];
    red[t] = acc;
    __syncthreads();
    for (int off = 128; off > 0; off >>= 1) {
        if (t < off) red[t] += red[t + off];
        __syncthreads();
    }
    if (t == 0) sumx[b] = red[0];
}

// int32 codes -> uint8, re-tiled so gemm block b, tile t reads ONE contiguous
// 16 KB chunk: wpk[((b*NT + t)*16 + r)*KT + k0],  r = n row within block.
// Reads are fully linear/coalesced (537 MB streaming); writes: each wave
// writes exactly one contiguous 1 KB row-chunk (write-combined in L2).
__global__ __launch_bounds__(256) void pack_kernel(
        const int* __restrict__ widx, unsigned char* __restrict__ wpk) {
    const long g  = (long)blockIdx.x * 256 + threadIdx.x;  // 8,388,608 threads
    const long i0 = g * 16;                                // first code index
    const int  n  = (int)(i0 >> 13);                       // row (8192 codes/row)
    const int  k  = (int)(i0 & 8191);
    const int  b  = n >> 4;
    const int  r  = n & 15;
    const int  t  = k >> 10;
    const int  k0 = k & 1023;
    const int4* src = (const int4*)(widx + i0);
    unsigned tmp[4];
    #pragma unroll
    for (int q = 0; q < 4; ++q) {
        int4 c = src[q];
        tmp[q] = (c.x & 255) | ((c.y & 255) << 8) |
                 ((c.z & 255) << 16) | ((unsigned)(c.w & 255) << 24);
    }
    uint4 o = {tmp[0], tmp[1], tmp[2], tmp[3]};
    *(uint4*)(wpk + (((long)(b * NT + t) * 16 + r) << 10) + k0) = o;
}

// One block per 16-row n-tile, full K. Stages uint8 codes from the packed,
// block-contiguous wpk: 16 KB/tile via 16 DMA instrs (1 row-chunk each),
// double-buffered with counted vmcnt(4) + raw s_barrier so next-tile loads
// stay in flight across the barrier (no vmcnt(0) drain in steady state).
// MFMA 16x16x32 bf16: A[m=lane&15][k=(lane>>4)*8+j], C/D col=lane&15,
// row=(lane>>4)*4+reg (validated in earlier rounds).
__global__ __launch_bounds__(256, 4) void gemm_kernel(
        const unsigned short* __restrict__ xbf,
        const unsigned char* __restrict__ wpk,
        const float* __restrict__ bias,
        const float* __restrict__ lut,
        const float* __restrict__ sumx,
        float* __restrict__ out) {
    __shared__ char ltile[2][16 * PITCH];        // 2 x 16,640 B = 33,280 B
    const int tid   = threadIdx.x;
    const int wave  = tid >> 6;
    const int lane  = tid & 63;
    const int col16 = lane & 15;
    const int quad  = lane >> 4;
    const int n0    = blockIdx.x * 16;

    const unsigned char* slab = wpk + ((long)blockIdx.x * NT) * (16 * KT);
    const unsigned short* xp0 = xbf + col16 * IN_F + quad * 8;  // m = col16
    const unsigned short* xp1 = xp0 + 16 * IN_F;                // m = col16+16

    f32x4 acc0 = {0.f, 0.f, 0.f, 0.f};
    f32x4 acc1 = {0.f, 0.f, 0.f, 0.f};

    // stage tile tt into buffer bb: wave w DMAs rows w*4..w*4+3 (1 KB each)
    #define STAGE(tt, bb)                                                     \
        _Pragma("unroll")                                                     \
        for (int j = 0; j < 4; ++j) {                                         \
            const int r_ = wave * 4 + j;                                      \
            async_copy16(slab + ((long)(tt) * 16 + r_) * KT + lane * 16,      \
                         &ltile[bb][r_ * PITCH]);                             \
        }

    STAGE(0, 0)
    for (int t = 0; t < NT; ++t) {
        if (t < NT - 1) {
            STAGE(t + 1, (t + 1) & 1)
            asm volatile("s_waitcnt vmcnt(4)" ::: "memory");  // tile t landed (own)
        } else {
            asm volatile("s_waitcnt vmcnt(0)" ::: "memory");
        }
        asm volatile("s_barrier" ::: "memory");               // all waves' tile t in LDS
        // compute: wave w consumes k sub-range [w*256, w*256+256) of the tile
        const char* base = &ltile[t & 1][col16 * PITCH + wave * 256 + quad * 8];
        #pragma unroll
        for (int s = 0; s < 8; ++s) {
            unsigned p0 = *(const unsigned*)(base + s * 32);
            unsigned p1 = *(const unsigned*)(base + s * 32 + 4);
            const int ka = t * KT + wave * 256 + s * 32;
            bf16x8 a0 = *(const bf16x8*)(xp0 + ka);
            bf16x8 a1 = *(const bf16x8*)(xp1 + ka);
            float f0 = (float)(p0 & 255u),         f1 = (float)((p0 >> 8) & 255u);
            float f2 = (float)((p0 >> 16) & 255u), f3 = (float)(p0 >> 24);
            float f4 = (float)(p1 & 255u),         f5 = (float)((p1 >> 8) & 255u);
            float f6 = (float)((p1 >> 16) & 255u), f7 = (float)(p1 >> 24);
            union { unsigned u[4]; bf16x8 v; } bB;
            bB.u[0] = pk_ff(f0, f1);
            bB.u[1] = pk_ff(f2, f3);
            bB.u[2] = pk_ff(f4, f5);
            bB.u[3] = pk_ff(f6, f7);
            acc0 = __builtin_amdgcn_mfma_f32_16x16x32_bf16(a0, bB.v, acc0, 0, 0, 0);
            acc1 = __builtin_amdgcn_mfma_f32_16x16x32_bf16(a1, bB.v, acc1, 0, 0, 0);
        }
        asm volatile("s_barrier" ::: "memory");  // done reading before overwrite
    }

    // epilogue: cross-wave (split-k within block) reduce via LDS, fuse
    // bias + lut[0]*sumx correction, direct store (out fully overwritten).
    float* red = (float*)ltile;                  // 4 x 512 floats = 8 KB
    #pragma unroll
    for (int r = 0; r < 4; ++r) {
        red[wave * 512 + (quad * 4 + r)      * 16 + col16] = acc0[r];
        red[wave * 512 + (quad * 4 + r + 16) * 16 + col16] = acc1[r];
    }
    __syncthreads();
    const float l0 = lut[0];                     // = -128*s
    #pragma unroll
    for (int e0 = 0; e0 < 2; ++e0) {
        const int e = tid + e0 * 256;            // 512 elems = 32 m x 16 n
        float v = red[e] + red[e + 512] + red[e + 1024] + red[e + 1536];
        const int m  = e >> 4;
        const int nn = e & 15;
        v += bias[n0 + nn] + l0 * sumx[m];
        out[(long)m * OUT_F + n0 + nn] = v;
    }
}

extern "C" void kernel_launch(void* const* d_in, const int* in_sizes, int n_in,
                              void* d_out, int out_size, void* d_ws, size_t ws_size,
                              hipStream_t stream) {
    const float* x    = (const float*)d_in[0];
    const float* lut  = (const float*)d_in[1];
    const float* bias = (const float*)d_in[2];
    const int*   widx = (const int*)d_in[3];
    float* out = (float*)d_out;

    unsigned short* xbf = (unsigned short*)d_ws;                    // 512 KiB
    float* sumx = (float*)((char*)d_ws + BATCH * IN_F * 2);         // 128 B
    unsigned char* wpk = (unsigned char*)d_ws + (1 << 20);          // 128 MiB packed codes

    prep_kernel<<<BATCH, 256, 0, stream>>>(x, lut, xbf, sumx);
    pack_kernel<<<(long)OUT_F * IN_F / 16 / 256, 256, 0, stream>>>(widx, wpk);
    gemm_kernel<<<OUT_F / 16, 256, 0, stream>>>(xbf, wpk, bias, lut, sumx, out);
}